// Round 1
// baseline (160.113 us; speedup 1.0000x reference)
//
#include <hip/hip_runtime.h>
#include <math.h>

// ANModel forward. Key structural facts exploited (see analysis):
//  - loop iteration i=0 is dead (x never updated); only i=1 params matter
//  - only 6 rows of x_adapt per batch are consumed (road_neighbor gather)
//  - emb linearity folds the (B,N,N,D) edge path into per-row weighted
//    reductions of edge_attrs with precomposed we3 = we@W3, be3 = be@W3

constexpr int Bc   = 8;
constexpr int Nc   = 512;
constexpr int Mc   = 6;
constexpr int EDc  = 8;
constexpr int SRCc = 64;
constexpr int OBSc = 32;
constexpr int Dc   = 16;
constexpr int Hc   = 64;

__global__ __launch_bounds__(512) void anmodel_kernel(
    const float* __restrict__ obs,        // (B,64)
    const float* __restrict__ obs_all,    // (B,512,32)
    const float* __restrict__ edge_attrs, // (B,512,512,8)
    const int*   __restrict__ ridxs,      // (B,)
    const int*   __restrict__ rni,        // (512,6)
    const int*   __restrict__ rnm,        // (512,6)
    const float* __restrict__ A,          // (512,512)
    const float* __restrict__ PA,         // (512,512)
    const float* __restrict__ w_src,      // (64,96)
    const float* __restrict__ b_src,      // (96,)
    const float* __restrict__ w_obs,      // (32,16)
    const float* __restrict__ b_obs,      // (16,)
    const float* __restrict__ res_w,      // (2,16,16)
    const float* __restrict__ res_b,      // (2,16)
    const float* __restrict__ ge_we,      // (2,8,16)
    const float* __restrict__ ge_be,      // (2,16)
    const float* __restrict__ ge_wemb,    // (2,48,16)
    const float* __restrict__ ge_bemb,    // (2,16)
    const float* __restrict__ gated_w,    // (192,32)
    const float* __restrict__ gated_b,    // (32,)
    const float* __restrict__ base_w1,    // (16,64)
    const float* __restrict__ base_b1,    // (64,)
    const float* __restrict__ base_w2,    // (64,64)
    const float* __restrict__ base_b2,    // (64,)
    const float* __restrict__ act_w,      // (64,6)
    const float* __restrict__ act_b,      // (6,)
    float* __restrict__ out)              // (B,6)
{
    const int b    = blockIdx.x;
    const int tid  = threadIdx.x;
    const int lane = tid & 63;
    const int wave = tid >> 6;

    __shared__ float s_y[Nc][Dc];        // 32 KB: y = x @ W2 for all nodes
    __shared__ float s_wobs[OBSc][Dc];
    __shared__ float s_bobs[Dc];
    __shared__ float s_W1[Dc][Dc];
    __shared__ float s_W2[Dc][Dc];
    __shared__ float s_resw[Dc][Dc];
    __shared__ float s_resb[Dc];
    __shared__ float s_we3[EDc][Dc];     // we[1] @ W3
    __shared__ float s_be3[Dc];          // be[1] @ W3
    __shared__ float s_bemb[Dc];
    __shared__ float s_sel[Mc * Dc];     // 96
    __shared__ float s_obsp[SRCc + 32];  // 96
    __shared__ float s_h0[Dc];
    __shared__ float s_h1[Hc];
    __shared__ float s_h2[Hc];

    // ---- Phase 0: stage small weights (i=1 params only) ----
    const float* wemb1 = ge_wemb + 3 * Dc * Dc;   // (48,16): W1|W2|W3 stacked
    for (int t = tid; t < OBSc * Dc; t += 512) s_wobs[t / Dc][t % Dc] = w_obs[t];
    for (int t = tid; t < Dc; t += 512) {
        s_bobs[t] = b_obs[t];
        s_resb[t] = res_b[Dc + t];
        s_bemb[t] = ge_bemb[Dc + t];
        float acc = 0.f;
        #pragma unroll
        for (int k = 0; k < Dc; ++k)
            acc = fmaf(ge_be[Dc + k], wemb1[(2 * Dc + k) * Dc + t], acc);
        s_be3[t] = acc;
    }
    for (int t = tid; t < Dc * Dc; t += 512) {
        s_W1[t / Dc][t % Dc]   = wemb1[t];
        s_W2[t / Dc][t % Dc]   = wemb1[Dc * Dc + t];
        s_resw[t / Dc][t % Dc] = res_w[Dc * Dc + t];
    }
    for (int t = tid; t < EDc * Dc; t += 512) {
        const int e = t / Dc, d = t % Dc;
        float acc = 0.f;
        #pragma unroll
        for (int k = 0; k < Dc; ++k)
            acc = fmaf(ge_we[EDc * Dc + e * Dc + k], wemb1[(2 * Dc + k) * Dc + d], acc);
        s_we3[e][d] = acc;
    }
    __syncthreads();

    // ---- Phase A: y[j][:] = (obs_all[b,j] @ w_obs + b_obs) @ W2 for all j ----
    {
        const int j = tid;
        const float* oa = obs_all + ((size_t)b * Nc + j) * OBSc;
        float o[OBSc];
        #pragma unroll
        for (int k = 0; k < OBSc; k += 4) {
            const float4 v = *reinterpret_cast<const float4*>(oa + k);
            o[k] = v.x; o[k + 1] = v.y; o[k + 2] = v.z; o[k + 3] = v.w;
        }
        float xv[Dc];
        #pragma unroll
        for (int d = 0; d < Dc; ++d) xv[d] = s_bobs[d];
        #pragma unroll
        for (int k = 0; k < OBSc; ++k) {
            const float ok = o[k];
            #pragma unroll
            for (int d = 0; d < Dc; ++d) xv[d] = fmaf(ok, s_wobs[k][d], xv[d]);
        }
        #pragma unroll
        for (int d = 0; d < Dc; ++d) {
            float acc = 0.f;
            #pragma unroll
            for (int k = 0; k < Dc; ++k) acc = fmaf(xv[k], s_W2[k][d], acc);
            s_y[j][d] = acc;
        }
    }
    __syncthreads();

    // ---- Phase B: waves 0..5 -> one selected row each; wave 6 -> obs_p ----
    if (wave < Mc) {
        const int m  = wave;
        const int r  = ridxs[b];
        const int i  = rni[r * Mc + m];
        const int mk = rnm[r * Mc + m];
        const float* Arow = A  + (size_t)i * Nc;
        const float* Prow = PA + (size_t)i * Nc;

        // deg[i] = sum_j (A+PA)[i,j]   -> butterfly to all lanes
        float dv = 0.f;
        #pragma unroll
        for (int t = 0; t < 8; ++t) {
            const int j = lane * 8 + t;
            dv += Arow[j] + Prow[j];
        }
        #pragma unroll
        for (int s = 1; s < 64; s <<= 1) dv += __shfl_xor(dv, s);

        // adjdot[d] = sum_j (A+PA)[i,j] * y[j][d]; lane = jg*16 + d
        const int dq = lane & 15, jg = lane >> 4;
        float adot = 0.f;
        for (int t = 0; t < Nc / 4; ++t) {
            const int j = t * 4 + jg;
            adot = fmaf(Arow[j] + Prow[j], s_y[j][dq], adot);
        }
        adot += __shfl_xor(adot, 16);
        adot += __shfl_xor(adot, 32);   // all lanes now hold adjdot[lane&15]

        // agge[e] = sum_j (A+PA)[i,j] * E[b,i,j,e]; lane = jg8*8 + e
        // global address = base + t*64 + lane  -> fully coalesced
        const int e8 = lane & 7, jg8 = lane >> 3;
        const float* Erow = edge_attrs + (((size_t)b * Nc + i) * Nc) * EDc;
        float ag = 0.f;
        for (int t = 0; t < Nc / 8; ++t) {
            const int j = t * 8 + jg8;
            ag = fmaf(Arow[j] + Prow[j], Erow[(size_t)j * EDc + e8], ag);
        }
        ag += __shfl_xor(ag, 8);
        ag += __shfl_xor(ag, 16);
        ag += __shfl_xor(ag, 32);       // all lanes hold agge[lane&7]
        float agv[EDc];
        #pragma unroll
        for (int e = 0; e < EDc; ++e) agv[e] = __shfl(ag, e);

        // x_i recomputed redundantly by every lane (cheap, avoids LDS sync)
        const float* oa = obs_all + ((size_t)b * Nc + i) * OBSc;
        float xi[Dc];
        #pragma unroll
        for (int d = 0; d < Dc; ++d) xi[d] = s_bobs[d];
        for (int k = 0; k < OBSc; ++k) {
            const float ok = oa[k];
            #pragma unroll
            for (int d = 0; d < Dc; ++d) xi[d] = fmaf(ok, s_wobs[k][d], xi[d]);
        }

        if (lane < Dc) {
            const int d = lane;
            float resv = s_resb[d];
            float w1t  = 0.f;
            #pragma unroll
            for (int k = 0; k < Dc; ++k) {
                resv = fmaf(xi[k], s_resw[k][d], resv);
                w1t  = fmaf(xi[k], s_W1[k][d], w1t);
            }
            float agdot = 0.f;
            #pragma unroll
            for (int e = 0; e < EDc; ++e) agdot = fmaf(agv[e], s_we3[e][d], agdot);
            float aggv = fmaf(w1t, dv, adot) + agdot + dv * s_be3[d] + s_bemb[d] * dv;
            float xa = resv + aggv;
            xa = xa > 0.f ? xa : 0.f;
            s_sel[m * Dc + d] = (mk == 0) ? -1.0f : xa;
        }
    } else if (wave == 6) {
        // obs_p = obs[b] @ w_src + b_src  (96 outputs)
        for (int t = lane; t < SRCc + 32; t += 64) {
            float acc = b_src[t];
            for (int s = 0; s < SRCc; ++s)
                acc = fmaf(obs[b * SRCc + s], w_src[s * 96 + t], acc);
            s_obsp[t] = acc;
        }
    }
    __syncthreads();

    // ---- Phase C: tiny MLP, wave 0 only, block barriers between steps ----
    if (wave == 0) {
        float gv = 0.f;
        if (lane < 32) {
            gv = gated_b[lane];
            for (int t = 0; t < 96; ++t) gv = fmaf(s_obsp[t], gated_w[t * 32 + lane], gv);
            for (int t = 0; t < 96; ++t) gv = fmaf(s_sel[t],  gated_w[(96 + t) * 32 + lane], gv);
        }
        const float gate = __shfl(gv, (lane & 15) + 16);
        if (lane < Dc) {
            s_h0[lane] = gv * (1.0f / (1.0f + expf(-gate)));
        }
    }
    __syncthreads();
    if (wave == 0) {
        float acc = base_b1[lane];
        #pragma unroll
        for (int k = 0; k < Dc; ++k) acc = fmaf(s_h0[k], base_w1[k * Hc + lane], acc);
        s_h1[lane] = acc > 0.f ? acc : 0.f;
    }
    __syncthreads();
    if (wave == 0) {
        float acc = base_b2[lane];
        #pragma unroll
        for (int k = 0; k < Hc; ++k) acc = fmaf(s_h1[k], base_w2[k * Hc + lane], acc);
        s_h2[lane] = acc > 0.f ? acc : 0.f;
    }
    __syncthreads();
    if (wave == 0 && lane < Mc) {
        float acc = act_b[lane];
        #pragma unroll
        for (int k = 0; k < Hc; ++k) acc = fmaf(s_h2[k], act_w[k * Mc + lane], acc);
        out[b * Mc + lane] = acc;
    }
}

extern "C" void kernel_launch(void* const* d_in, const int* in_sizes, int n_in,
                              void* d_out, int out_size, void* d_ws, size_t ws_size,
                              hipStream_t stream) {
    (void)in_sizes; (void)n_in; (void)d_ws; (void)ws_size; (void)out_size;
    anmodel_kernel<<<dim3(Bc), dim3(512), 0, stream>>>(
        (const float*)d_in[0],  (const float*)d_in[1],  (const float*)d_in[2],
        (const int*)  d_in[3],  (const int*)  d_in[4],  (const int*)  d_in[5],
        (const float*)d_in[6],  (const float*)d_in[7],  (const float*)d_in[8],
        (const float*)d_in[9],  (const float*)d_in[10], (const float*)d_in[11],
        (const float*)d_in[12], (const float*)d_in[13], (const float*)d_in[14],
        (const float*)d_in[15], (const float*)d_in[16], (const float*)d_in[17],
        (const float*)d_in[18], (const float*)d_in[19], (const float*)d_in[20],
        (const float*)d_in[21], (const float*)d_in[22], (const float*)d_in[23],
        (const float*)d_in[24], (const float*)d_in[25],
        (float*)d_out);
}

// Round 2
// 151.929 us; speedup vs baseline: 1.0539x; 1.0539x over previous
//
#include <hip/hip_runtime.h>
#include <math.h>

// ANModel forward, round 2.
// Structural reductions (all verified exact in R1, absmax 0.0):
//  - loop iteration i=0 is dead; only i=1 params matter
//  - only 6 rows of x_adapt per batch are consumed
//  - emb linearity folds the edge path: we3 = we@W3, be3 = be@W3
// New in R2:
//  - adjdot = (sum_j w[j] x[j]) @ W2  (linearity: drop per-node @W2, drop s_y)
//  - A+PA rows staged to LDS once (coalesced) instead of broadcast global reads
//  - wave 7 put to work on obs_p; xi read from s_x instead of recomputed

constexpr int Bc   = 8;
constexpr int Nc   = 512;
constexpr int Mc   = 6;
constexpr int EDc  = 8;
constexpr int SRCc = 64;
constexpr int OBSc = 32;
constexpr int Dc   = 16;
constexpr int Hc   = 64;

__global__ __launch_bounds__(512) void anmodel_kernel(
    const float* __restrict__ obs,        // (B,64)
    const float* __restrict__ obs_all,    // (B,512,32)
    const float* __restrict__ edge_attrs, // (B,512,512,8)
    const int*   __restrict__ ridxs,      // (B,)
    const int*   __restrict__ rni,        // (512,6)
    const int*   __restrict__ rnm,        // (512,6)
    const float* __restrict__ A,          // (512,512)
    const float* __restrict__ PA,         // (512,512)
    const float* __restrict__ w_src,      // (64,96)
    const float* __restrict__ b_src,      // (96,)
    const float* __restrict__ w_obs,      // (32,16)
    const float* __restrict__ b_obs,      // (16,)
    const float* __restrict__ res_w,      // (2,16,16)
    const float* __restrict__ res_b,      // (2,16)
    const float* __restrict__ ge_we,      // (2,8,16)
    const float* __restrict__ ge_be,      // (2,16)
    const float* __restrict__ ge_wemb,    // (2,48,16)
    const float* __restrict__ ge_bemb,    // (2,16)
    const float* __restrict__ gated_w,    // (192,32)
    const float* __restrict__ gated_b,    // (32,)
    const float* __restrict__ base_w1,    // (16,64)
    const float* __restrict__ base_b1,    // (64,)
    const float* __restrict__ base_w2,    // (64,64)
    const float* __restrict__ base_b2,    // (64,)
    const float* __restrict__ act_w,      // (64,6)
    const float* __restrict__ act_b,      // (6,)
    float* __restrict__ out)              // (B,6)
{
    const int b    = blockIdx.x;
    const int tid  = threadIdx.x;
    const int lane = tid & 63;
    const int wave = tid >> 6;

    __shared__ float s_x[Nc][Dc];        // 32 KB: x = obs_all@w_obs + b_obs
    __shared__ float s_w[Mc][Nc];        // 12 KB: (A+PA) rows of selected nodes
    __shared__ float s_wobs[OBSc][Dc];
    __shared__ float s_bobs[Dc];
    __shared__ float s_W1[Dc][Dc];
    __shared__ float s_W2[Dc][Dc];
    __shared__ float s_resw[Dc][Dc];
    __shared__ float s_resb[Dc];
    __shared__ float s_we3[EDc][Dc];     // we[1] @ W3
    __shared__ float s_be3[Dc];          // be[1] @ W3
    __shared__ float s_bemb[Dc];
    __shared__ int   s_idx[Mc];
    __shared__ int   s_msk[Mc];
    __shared__ float s_sel[Mc * Dc];     // 96
    __shared__ float s_obsp[SRCc + 32];  // 96
    __shared__ float s_h0[Dc];
    __shared__ float s_h1[Hc];
    __shared__ float s_h2[Hc];

    // ---- Phase 0: stage small weights (i=1 params only) + selected indices ----
    const float* wemb1 = ge_wemb + 3 * Dc * Dc;   // (48,16): W1|W2|W3 stacked
    for (int t = tid; t < OBSc * Dc; t += 512) s_wobs[t / Dc][t % Dc] = w_obs[t];
    for (int t = tid; t < Dc; t += 512) {
        s_bobs[t] = b_obs[t];
        s_resb[t] = res_b[Dc + t];
        s_bemb[t] = ge_bemb[Dc + t];
        float acc = 0.f;
        #pragma unroll
        for (int k = 0; k < Dc; ++k)
            acc = fmaf(ge_be[Dc + k], wemb1[(2 * Dc + k) * Dc + t], acc);
        s_be3[t] = acc;
    }
    for (int t = tid; t < Dc * Dc; t += 512) {
        s_W1[t / Dc][t % Dc]   = wemb1[t];
        s_W2[t / Dc][t % Dc]   = wemb1[Dc * Dc + t];
        s_resw[t / Dc][t % Dc] = res_w[Dc * Dc + t];
    }
    for (int t = tid; t < EDc * Dc; t += 512) {
        const int e = t / Dc, d = t % Dc;
        float acc = 0.f;
        #pragma unroll
        for (int k = 0; k < Dc; ++k)
            acc = fmaf(ge_we[EDc * Dc + e * Dc + k], wemb1[(2 * Dc + k) * Dc + d], acc);
        s_we3[e][d] = acc;
    }
    if (tid < Mc) {
        const int r = ridxs[b];
        s_idx[tid] = rni[r * Mc + tid];
        s_msk[tid] = rnm[r * Mc + tid];
    }
    __syncthreads();

    // ---- Phase A: x[j] for all j (thread j), plus coalesced (A+PA) row staging ----
    {
        const int j = tid;
        const float* oa = obs_all + ((size_t)b * Nc + j) * OBSc;
        float o[OBSc];
        #pragma unroll
        for (int k = 0; k < OBSc; k += 4) {
            const float4 v = *reinterpret_cast<const float4*>(oa + k);
            o[k] = v.x; o[k + 1] = v.y; o[k + 2] = v.z; o[k + 3] = v.w;
        }
        float xv[Dc];
        #pragma unroll
        for (int d = 0; d < Dc; ++d) xv[d] = s_bobs[d];
        #pragma unroll
        for (int k = 0; k < OBSc; ++k) {
            const float ok = o[k];
            #pragma unroll
            for (int d = 0; d < Dc; ++d) xv[d] = fmaf(ok, s_wobs[k][d], xv[d]);
        }
        #pragma unroll
        for (int d = 0; d < Dc; ++d) s_x[j][d] = xv[d];
    }
    #pragma unroll
    for (int m = 0; m < Mc; ++m) {
        const int i = s_idx[m];
        s_w[m][tid] = A[(size_t)i * Nc + tid] + PA[(size_t)i * Nc + tid];
    }
    __syncthreads();

    // ---- Phase B: waves 0..5 -> one selected row each; waves 6,7 -> obs_p ----
    if (wave < Mc) {
        const int m = wave;
        const float* __restrict__ wrow = &s_w[m][0];

        // deg = sum_j w[j] ; conflict-free stride-64 LDS reads, then butterfly
        float dv = 0.f;
        #pragma unroll
        for (int t = 0; t < Nc / 64; ++t) dv += wrow[t * 64 + lane];
        #pragma unroll
        for (int s = 1; s < 64; s <<= 1) dv += __shfl_xor(dv, s);

        // wx[d] = sum_j w[j] * x[j][d]; lane = jg*16 + d (4-way j split)
        // s_x access: 4 distinct j per instr -> 2 lanes/bank (free)
        const int dq = lane & 15, jg = lane >> 4;
        float wx = 0.f;
        #pragma unroll 8
        for (int t = 0; t < Nc / 4; ++t) {
            const int j = t * 4 + jg;
            wx = fmaf(wrow[j], s_x[j][dq], wx);
        }
        wx += __shfl_xor(wx, 16);
        wx += __shfl_xor(wx, 32);       // all lanes hold wx[lane&15]
        float wxv[Dc];
        #pragma unroll
        for (int k = 0; k < Dc; ++k) wxv[k] = __shfl(wx, k);

        // agge[e] = sum_j w[j] * E[b,i,j,e]; global addr = base + t*64 + lane
        const int e8 = lane & 7, jg8 = lane >> 3;
        const int i  = s_idx[m];
        const float* __restrict__ Erow = edge_attrs + (((size_t)b * Nc + i) * Nc) * EDc;
        float ag = 0.f;
        #pragma unroll 4
        for (int t = 0; t < Nc / 8; ++t) {
            const int j = t * 8 + jg8;
            ag = fmaf(wrow[j], Erow[(size_t)j * EDc + e8], ag);
        }
        ag += __shfl_xor(ag, 8);
        ag += __shfl_xor(ag, 16);
        ag += __shfl_xor(ag, 32);
        float agv[EDc];
        #pragma unroll
        for (int e = 0; e < EDc; ++e) agv[e] = __shfl(ag, e);

        if (lane < Dc) {
            const int d = lane;
            float resv = s_resb[d];
            float w1t  = 0.f;
            float adot = 0.f;
            #pragma unroll
            for (int k = 0; k < Dc; ++k) {
                const float xik = s_x[i][k];
                resv = fmaf(xik, s_resw[k][d], resv);
                w1t  = fmaf(xik, s_W1[k][d], w1t);
                adot = fmaf(wxv[k], s_W2[k][d], adot);   // adjdot = wx @ W2
            }
            float agdot = 0.f;
            #pragma unroll
            for (int e = 0; e < EDc; ++e) agdot = fmaf(agv[e], s_we3[e][d], agdot);
            float aggv = fmaf(w1t, dv, adot) + agdot + dv * (s_be3[d] + s_bemb[d]);
            float xa = resv + aggv;
            xa = xa > 0.f ? xa : 0.f;
            s_sel[m * Dc + d] = (s_msk[m] == 0) ? -1.0f : xa;
        }
    } else {
        // obs_p = obs[b] @ w_src + b_src (96 outputs across waves 6,7)
        const int t = (wave - 6) * 64 + lane;
        if (t < SRCc + 32) {
            float acc = b_src[t];
            #pragma unroll 8
            for (int s = 0; s < SRCc; ++s)
                acc = fmaf(obs[b * SRCc + s], w_src[s * 96 + t], acc);
            s_obsp[t] = acc;
        }
    }
    __syncthreads();

    // ---- Phase C: tiny MLP, wave 0 only, block barriers between steps ----
    if (wave == 0) {
        float gv = 0.f;
        if (lane < 32) {
            gv = gated_b[lane];
            for (int t = 0; t < 96; ++t) gv = fmaf(s_obsp[t], gated_w[t * 32 + lane], gv);
            for (int t = 0; t < 96; ++t) gv = fmaf(s_sel[t],  gated_w[(96 + t) * 32 + lane], gv);
        }
        const float gate = __shfl(gv, (lane & 15) + 16);
        if (lane < Dc) {
            s_h0[lane] = gv * (1.0f / (1.0f + expf(-gate)));
        }
    }
    __syncthreads();
    if (wave == 0) {
        float acc = base_b1[lane];
        #pragma unroll
        for (int k = 0; k < Dc; ++k) acc = fmaf(s_h0[k], base_w1[k * Hc + lane], acc);
        s_h1[lane] = acc > 0.f ? acc : 0.f;
    }
    __syncthreads();
    if (wave == 0) {
        float acc = base_b2[lane];
        #pragma unroll
        for (int k = 0; k < Hc; ++k) acc = fmaf(s_h1[k], base_w2[k * Hc + lane], acc);
        s_h2[lane] = acc > 0.f ? acc : 0.f;
    }
    __syncthreads();
    if (wave == 0 && lane < Mc) {
        float acc = act_b[lane];
        #pragma unroll
        for (int k = 0; k < Hc; ++k) acc = fmaf(s_h2[k], act_w[k * Mc + lane], acc);
        out[b * Mc + lane] = acc;
    }
}

extern "C" void kernel_launch(void* const* d_in, const int* in_sizes, int n_in,
                              void* d_out, int out_size, void* d_ws, size_t ws_size,
                              hipStream_t stream) {
    (void)in_sizes; (void)n_in; (void)d_ws; (void)ws_size; (void)out_size;
    anmodel_kernel<<<dim3(Bc), dim3(512), 0, stream>>>(
        (const float*)d_in[0],  (const float*)d_in[1],  (const float*)d_in[2],
        (const int*)  d_in[3],  (const int*)  d_in[4],  (const int*)  d_in[5],
        (const float*)d_in[6],  (const float*)d_in[7],  (const float*)d_in[8],
        (const float*)d_in[9],  (const float*)d_in[10], (const float*)d_in[11],
        (const float*)d_in[12], (const float*)d_in[13], (const float*)d_in[14],
        (const float*)d_in[15], (const float*)d_in[16], (const float*)d_in[17],
        (const float*)d_in[18], (const float*)d_in[19], (const float*)d_in[20],
        (const float*)d_in[21], (const float*)d_in[22], (const float*)d_in[23],
        (const float*)d_in[24], (const float*)d_in[25],
        (float*)d_out);
}